// Round 1
// baseline (252.531 us; speedup 1.0000x reference)
//
#include <hip/hip_runtime.h>

// Problem constants (from reference setup_inputs): B=8, H=512, W=512, C=16.
// dense_image_warp: out[b,h,w,c] = bilinear(img, h - flow[b,h,w,0], w - flow[b,h,w,1])
// with tfa semantics: floor clipped to [0, size-2], alpha clipped to [0,1].

constexpr int B = 8;
constexpr int H = 512;
constexpr int W = 512;
constexpr int C = 16;

// 4 lanes per output pixel; each lane handles 4 channels (float4 = 16 B/lane).
// Consecutive lanes -> consecutive 16B chunks: coalesced stores; each corner
// gather is one 64B line shared by the quad.
__global__ __launch_bounds__(256) void warp_kernel(
    const float* __restrict__ img,
    const float* __restrict__ flow,
    float* __restrict__ out)
{
    const int tid = blockIdx.x * blockDim.x + threadIdx.x;
    const int p  = tid >> 2;          // pixel index in [0, B*H*W)
    const int c0 = (tid & 3) << 2;    // channel offset: 0,4,8,12

    // decompose p -> (b, h, w); W=512 -> 9 bits, H=512 -> 9 bits
    const int w = p & (W - 1);
    const int h = (p >> 9) & (H - 1);
    const int b = p >> 18;

    // flow[b,h,w,{0,1}] — same address across the 4 lanes of a quad (broadcast)
    const float2 f = *reinterpret_cast<const float2*>(flow + 2 * (size_t)p);

    const float qy = (float)h - f.x;
    const float qx = (float)w - f.y;

    float fy = fminf(fmaxf(floorf(qy), 0.0f), (float)(H - 2));
    float fx = fminf(fmaxf(floorf(qx), 0.0f), (float)(W - 2));
    const float ay = fminf(fmaxf(qy - fy, 0.0f), 1.0f);
    const float ax = fminf(fmaxf(qx - fx, 0.0f), 1.0f);
    const int iy = (int)fy;
    const int ix = (int)fx;

    const size_t rowStride = (size_t)W * C;
    const float* base = img + ((size_t)((b * H + iy) * W + ix) * C + c0);

    const float4 tl = *reinterpret_cast<const float4*>(base);
    const float4 tr = *reinterpret_cast<const float4*>(base + C);
    const float4 bl = *reinterpret_cast<const float4*>(base + rowStride);
    const float4 br = *reinterpret_cast<const float4*>(base + rowStride + C);

    // interp_top = tl + ax*(tr-tl); interp_bottom = bl + ax*(br-bl);
    // out = interp_top + ay*(interp_bottom - interp_top)  (reference order)
    float4 o;
    {
        const float t0 = tl.x + ax * (tr.x - tl.x);
        const float b0 = bl.x + ax * (br.x - bl.x);
        o.x = t0 + ay * (b0 - t0);
    }
    {
        const float t1 = tl.y + ax * (tr.y - tl.y);
        const float b1 = bl.y + ax * (br.y - bl.y);
        o.y = t1 + ay * (b1 - t1);
    }
    {
        const float t2 = tl.z + ax * (tr.z - tl.z);
        const float b2 = bl.z + ax * (br.z - bl.z);
        o.z = t2 + ay * (b2 - t2);
    }
    {
        const float t3 = tl.w + ax * (tr.w - tl.w);
        const float b3 = bl.w + ax * (br.w - bl.w);
        o.w = t3 + ay * (b3 - t3);
    }

    *reinterpret_cast<float4*>(out + (size_t)p * C + c0) = o;
}

extern "C" void kernel_launch(void* const* d_in, const int* in_sizes, int n_in,
                              void* d_out, int out_size, void* d_ws, size_t ws_size,
                              hipStream_t stream) {
    const float* img  = (const float*)d_in[0];   // [B,H,W,C] fp32
    const float* flow = (const float*)d_in[1];   // [B,H,W,2] fp32
    float* out = (float*)d_out;                  // [B,H,W,C] fp32

    // total threads = B*H*W*4 = 8,388,608 -> exact fit
    const int total = B * H * W * 4;
    const int block = 256;
    const int grid = total / block;  // 32768
    warp_kernel<<<grid, block, 0, stream>>>(img, flow, out);
}